// Round 4
// baseline (510.514 us; speedup 1.0000x reference)
//
#include <hip/hip_runtime.h>
#include <hip/hip_bf16.h>

typedef __hip_bfloat16 bf16;
typedef short bf16x8 __attribute__((ext_vector_type(8)));
typedef float f32x4 __attribute__((ext_vector_type(4)));

__device__ __forceinline__ float gelu_f(float x) {
  return 0.5f * x * (1.f + erff(x * 0.70710678118654752f));
}

__device__ __forceinline__ unsigned short f2bfu(float f) {
  bf16 h = __float2bfloat16(f);
  unsigned short u;
  __builtin_memcpy(&u, &h, 2);
  return u;
}

// async 16B/lane global->LDS; lds dest is wave-uniform base + lane*16
__device__ __forceinline__ void load16_lds(const bf16* g, bf16* l) {
  __builtin_amdgcn_global_load_lds(
      (const __attribute__((address_space(1))) unsigned int*)g,
      (__attribute__((address_space(3))) unsigned int*)l, 16, 0, 0);
}

// ---------------- weight transpose + cast: src fp32 [R][C] -> dst bf16 [C][R]
__global__ __launch_bounds__(256) void transpose_cast(
    const float* __restrict__ src, bf16* __restrict__ dst, int R, int C) {
  __shared__ float tile[32][33];
  int tx = threadIdx.x & 31, ty = threadIdx.x >> 5;  // 32 x 8
  int r0 = blockIdx.y * 32, c0 = blockIdx.x * 32;
  #pragma unroll
  for (int i = ty; i < 32; i += 8)
    tile[i][tx] = src[(size_t)(r0 + i) * C + (c0 + tx)];
  __syncthreads();
  #pragma unroll
  for (int i = ty; i < 32; i += 8)
    dst[(size_t)(c0 + i) * R + (r0 + tx)] = __float2bfloat16(tile[tx][i]);
}

// ---------------- LayerNorm: x fp32 [rows][1024] -> y bf16, one block per row
__global__ __launch_bounds__(256) void ln_kernel(
    const float* __restrict__ x, const float* __restrict__ g,
    const float* __restrict__ b, bf16* __restrict__ y) {
  int row = blockIdx.x;
  int t = threadIdx.x;
  const float4* xr = (const float4*)(x + (size_t)row * 1024);
  float4 v = xr[t];
  float s = v.x + v.y + v.z + v.w;
  float ss = v.x * v.x + v.y * v.y + v.z * v.z + v.w * v.w;
  #pragma unroll
  for (int off = 32; off >= 1; off >>= 1) {
    s += __shfl_xor(s, off);
    ss += __shfl_xor(ss, off);
  }
  __shared__ float red[8];
  int wv = t >> 6;
  if ((t & 63) == 0) { red[wv] = s; red[4 + wv] = ss; }
  __syncthreads();
  float S = red[0] + red[1] + red[2] + red[3];
  float SS = red[4] + red[5] + red[6] + red[7];
  float mu = S * (1.f / 1024.f);
  float var = SS * (1.f / 1024.f) - mu * mu;
  float inv = rsqrtf(var + 1e-5f);
  float4 gv = ((const float4*)g)[t];
  float4 bv = ((const float4*)b)[t];
  ushort4 o;
  o.x = f2bfu((v.x - mu) * inv * gv.x + bv.x);
  o.y = f2bfu((v.y - mu) * inv * gv.y + bv.y);
  o.z = f2bfu((v.z - mu) * inv * gv.z + bv.z);
  o.w = f2bfu((v.w - mu) * inv * gv.w + bv.w);
  ((ushort4*)(y + (size_t)row * 1024))[t] = o;
}

// ---------------- GEMM: C = A[M][K] @ Bt[N][K]^T + bias
// m97 pattern + XCD-friendly macro-tile swizzle: 1D grid, 8x8-block macro
// tiles (A 2MB + B 2MB working set = one XCD L2) so staging loads hit L2.
// EPI 0: fused QKV epilogue (block-uniform n0>>10 selects q/k/v layout)
// EPI 3: fp32 out = val + resid
// EPI 4: bf16 out = gelu(val)
// EPI 5: fp32 out = gelu(val) + resid
template <int EPI>
__global__ __launch_bounds__(256) void gemm_bf16(
    const bf16* __restrict__ A, const bf16* __restrict__ Bt,
    const float* __restrict__ bias0, const float* __restrict__ bias1,
    const float* __restrict__ bias2, const float* __restrict__ resid,
    void* __restrict__ C0, void* __restrict__ C1, void* __restrict__ C2,
    int M, int N, int K) {
  __shared__ __align__(16) bf16 As[2][128 * 32];
  __shared__ __align__(16) bf16 Bs[2][128 * 32];
  const int t = threadIdx.x, lane = t & 63, w = t >> 6;
  const int wm = (w >> 1) * 64, wn = (w & 1) * 64;

  // macro-tile swizzle: 8x8 blocks per macro-tile, n-major macro order
  const int gx = N >> 7;           // n-blocks
  const int mtn = gx >> 3;         // macro-tiles per n row
  const int bid = blockIdx.x;
  const int mt = bid >> 6, within = bid & 63;
  const int mt_n = mt % mtn, mt_m = mt / mtn;
  const int n0 = ((mt_n << 3) + (within & 7)) << 7;
  const int m0 = ((mt_m << 3) + (within >> 3)) << 7;

  const int srow = lane >> 2;   // row within 16-row staging chunk
  const int sgrp = lane & 3;    // LDS col-group position this lane fills
  f32x4 acc[4][4] = {};

  const bf16* Abase = A + (size_t)m0 * K;
  const bf16* Bbase = Bt + (size_t)n0 * K;

  auto stage = [&](int buf, int kt) {
    #pragma unroll
    for (int c = 0; c < 2; ++c) {
      int row = w * 32 + c * 16 + srow;
      int sw = (row & 3) ^ ((row >> 2) & 3);
      int gg = sgrp ^ sw;  // global col-group this lane fetches (swizzled)
      const bf16* ga = Abase + (size_t)row * K + kt + gg * 8;
      const bf16* gb = Bbase + (size_t)row * K + kt + gg * 8;
      load16_lds(ga, &As[buf][(w * 32 + c * 16) * 32]);
      load16_lds(gb, &Bs[buf][(w * 32 + c * 16) * 32]);
    }
  };

  // fragment read col-group (swizzle inverse), uniform over mc/nc:
  // row = (mult of 16) + (lane&15) -> sw = (lane&3)^((lane>>2)&3)
  const int q8 = (((lane >> 4) ^ (lane & 3) ^ ((lane >> 2) & 3))) * 8;
  const int fr = lane & 15;

  const int nk = K >> 5;
  stage(0, 0);
  for (int i = 0; i < nk; ++i) {
    const int cur = i & 1;
    __syncthreads();  // drains vmcnt (staged loads for cur) + barrier
    if (i + 1 < nk) stage(cur ^ 1, (i + 1) << 5);
    bf16x8 af[4], bfr[4];
    #pragma unroll
    for (int mc = 0; mc < 4; ++mc)
      af[mc] = *(const bf16x8*)&As[cur][(wm + mc * 16 + fr) * 32 + q8];
    #pragma unroll
    for (int nc = 0; nc < 4; ++nc)
      bfr[nc] = *(const bf16x8*)&Bs[cur][(wn + nc * 16 + fr) * 32 + q8];
    #pragma unroll
    for (int mc = 0; mc < 4; ++mc)
      #pragma unroll
      for (int nc = 0; nc < 4; ++nc)
        acc[mc][nc] = __builtin_amdgcn_mfma_f32_16x16x32_bf16(
            af[mc], bfr[nc], acc[mc][nc], 0, 0, 0);
  }

  if constexpr (EPI == 0) {
    const int which = n0 >> 10;  // block-uniform: 0=q, 1=k, 2=v
    const float* bp = which == 0 ? bias0 : which == 1 ? bias1 : bias2;
    bf16* qk = (bf16*)(which == 0 ? C0 : C1);
    #pragma unroll
    for (int mc = 0; mc < 4; ++mc) {
      #pragma unroll
      for (int reg = 0; reg < 4; ++reg) {
        int m = m0 + wm + mc * 16 + ((lane >> 4) << 2) + reg;
        int b = m >> 11, tok = m & 2047;
        #pragma unroll
        for (int nc = 0; nc < 4; ++nc) {
          int n = n0 + wn + nc * 16 + (lane & 15);
          int nn = n & 1023, hh = nn >> 6, d = n & 63;
          float val = acc[mc][nc][reg] + bp[nn];
          if (which == 2)
            ((bf16*)C2)[(size_t)((b * 16 + hh) * 64 + d) * 2048 + tok] =
                __float2bfloat16(val);
          else
            qk[(size_t)((b * 16 + hh) * 2048 + tok) * 64 + d] =
                __float2bfloat16(val);
        }
      }
    }
  } else {
    #pragma unroll
    for (int mc = 0; mc < 4; ++mc) {
      #pragma unroll
      for (int reg = 0; reg < 4; ++reg) {
        int m = m0 + wm + mc * 16 + ((lane >> 4) << 2) + reg;
        #pragma unroll
        for (int nc = 0; nc < 4; ++nc) {
          int n = n0 + wn + nc * 16 + (lane & 15);
          float val = acc[mc][nc][reg] + bias0[n];
          size_t idx = (size_t)m * N + n;
          if constexpr (EPI == 3) {
            ((float*)C0)[idx] = val + resid[idx];
          } else if constexpr (EPI == 4) {
            ((bf16*)C0)[idx] = __float2bfloat16(gelu_f(val));
          } else {
            ((float*)C0)[idx] = gelu_f(val) + resid[idx];
          }
        }
      }
    }
  }
}

// ---------------- Flash attention with off-by-one softmax + head slimming
// Deferred-max variant: p = exp2(z*c) accumulated raw (scores are small; no
// overflow possible for |z| < ~5600). Off-by-one identity:
//   exp(a-m)/(1+sum exp(a-m)) == exp(a)/(exp(m)+sum exp(a))
// so denom = exp2(m*c) + l, reduced ONCE at the end (no per-tile reductions,
// no rescaling of o_acc).
// q,k: [B*H][2048][64] bf16 ; vt: [B*H][64][2048] bf16
// attn out: [4096][1024] bf16  (token-major, col = h*64+d)
__global__ __launch_bounds__(256) void attn_kernel(
    const bf16* __restrict__ q, const bf16* __restrict__ k,
    const bf16* __restrict__ vt, const float* __restrict__ slim,
    bf16* __restrict__ attn) {
  // non-padded tiles, XOR-swizzled placement: LDS[r][pos] = global[r][pos^(r&7)]
  __shared__ __align__(16) bf16 Ks[64][64];
  __shared__ __align__(16) bf16 Vs[64][64];
  __shared__ __align__(16) bf16 Ps[4][16][72];

  const int t = threadIdx.x, lane = t & 63, w = t >> 6;
  const int fr = lane & 15, qd = lane >> 4;
  const int bh = blockIdx.y;
  const int q0 = blockIdx.x * 64;
  const size_t bhbase = (size_t)bh * 2048 * 64;

  const int qrow = q0 + w * 16 + fr;
  const bf16* qp = q + bhbase + (size_t)qrow * 64 + qd * 8;
  bf16x8 qf0 = *(const bf16x8*)qp;
  bf16x8 qf1 = *(const bf16x8*)(qp + 32);

  // staging: wave w stages rows [w*16, w*16+16) of each tile, 2 insts each
  const int srow = lane >> 3;   // 0..7 within 8-row chunk
  const int sg = lane & 7;      // LDS 16B-group position this lane fills

  f32x4 o_acc[4] = {};
  float m_lane[4] = {-3.0e38f, -3.0e38f, -3.0e38f, -3.0e38f};
  float l_lane[4] = {0.f, 0.f, 0.f, 0.f};
  const float C = 0.18033688011f;  // 0.125 * log2(e)

  for (int j0 = 0; j0 < 2048; j0 += 64) {
    __syncthreads();
    #pragma unroll
    for (int c = 0; c < 2; ++c) {
      int r = w * 16 + c * 8 + srow;
      int gk = sg ^ (r & 7);  // swizzled global group
      load16_lds(k + bhbase + (size_t)(j0 + r) * 64 + gk * 8, &Ks[w * 16 + c * 8][0]);
      load16_lds(vt + bhbase + (size_t)r * 2048 + j0 + gk * 8, &Vs[w * 16 + c * 8][0]);
    }
    __syncthreads();

    // S = Q K^T (unscaled) for this wave's 16 rows x 64 cols
    f32x4 z[4];
    #pragma unroll
    for (int nc = 0; nc < 4; ++nc) {
      int kr = nc * 16 + fr;
      bf16x8 kf0 = *(const bf16x8*)&Ks[kr][(qd ^ (kr & 7)) * 8];
      bf16x8 kf1 = *(const bf16x8*)&Ks[kr][((qd + 4) ^ (kr & 7)) * 8];
      f32x4 zz = {};
      zz = __builtin_amdgcn_mfma_f32_16x16x32_bf16(qf0, kf0, zz, 0, 0, 0);
      zz = __builtin_amdgcn_mfma_f32_16x16x32_bf16(qf1, kf1, zz, 0, 0, 0);
      z[nc] = zz;
    }

    // p = exp2(z*C); per-lane running sum & max only (no cross-lane here)
    #pragma unroll
    for (int nc = 0; nc < 4; ++nc)
      #pragma unroll
      for (int r = 0; r < 4; ++r) {
        float p = exp2f(z[nc][r] * C);
        l_lane[r] += p;
        m_lane[r] = fmaxf(m_lane[r], z[nc][r]);
        Ps[w][qd * 4 + r][nc * 16 + fr] = __float2bfloat16(p);
      }

    // Ps is per-wave: intra-wave lgkmcnt ordering suffices (no barrier)
    bf16x8 pf0 = *(const bf16x8*)&Ps[w][fr][qd * 8];
    bf16x8 pf1 = *(const bf16x8*)&Ps[w][fr][32 + qd * 8];
    #pragma unroll
    for (int dc = 0; dc < 4; ++dc) {
      int vr = dc * 16 + fr;
      bf16x8 vf0 = *(const bf16x8*)&Vs[vr][(qd ^ (vr & 7)) * 8];
      bf16x8 vf1 = *(const bf16x8*)&Vs[vr][((qd + 4) ^ (vr & 7)) * 8];
      o_acc[dc] = __builtin_amdgcn_mfma_f32_16x16x32_bf16(pf0, vf0, o_acc[dc], 0, 0, 0);
      o_acc[dc] = __builtin_amdgcn_mfma_f32_16x16x32_bf16(pf1, vf1, o_acc[dc], 0, 0, 0);
    }
  }

  // final reductions over the 16 lanes holding each row's columns
  #pragma unroll
  for (int off = 1; off <= 8; off <<= 1)
    #pragma unroll
    for (int r = 0; r < 4; ++r) {
      l_lane[r] += __shfl_xor(l_lane[r], off);
      m_lane[r] = fmaxf(m_lane[r], __shfl_xor(m_lane[r], off));
    }

  const int b = bh >> 4, hh = bh & 15;
  const float sl = slim[hh];
  #pragma unroll
  for (int r = 0; r < 4; ++r) {
    float inv = sl / (exp2f(m_lane[r] * C) + l_lane[r]);
    int mrow = b * 2048 + q0 + w * 16 + qd * 4 + r;
    #pragma unroll
    for (int dc = 0; dc < 4; ++dc) {
      int col = hh * 64 + dc * 16 + fr;
      attn[(size_t)mrow * 1024 + col] = __float2bfloat16(o_acc[dc][r] * inv);
    }
  }
}

extern "C" void kernel_launch(void* const* d_in, const int* in_sizes, int n_in,
                              void* d_out, int out_size, void* d_ws, size_t ws_size,
                              hipStream_t stream) {
  const float* x    = (const float*)d_in[0];
  const float* ln1g = (const float*)d_in[1];
  const float* ln1b = (const float*)d_in[2];
  const float* Wq   = (const float*)d_in[3];
  const float* bq   = (const float*)d_in[4];
  const float* Wk   = (const float*)d_in[5];
  const float* bk   = (const float*)d_in[6];
  const float* Wv   = (const float*)d_in[7];
  const float* bv   = (const float*)d_in[8];
  const float* Wo   = (const float*)d_in[9];
  const float* bo   = (const float*)d_in[10];
  const float* slim = (const float*)d_in[11];
  const float* ln2g = (const float*)d_in[12];
  const float* ln2b = (const float*)d_in[13];
  const float* W1   = (const float*)d_in[14];
  const float* b1   = (const float*)d_in[15];
  const float* W2   = (const float*)d_in[16];
  const float* b2   = (const float*)d_in[17];

  char* p = (char*)d_ws;
  auto take = [&](size_t nbytes) {
    char* r = p;
    p += (nbytes + 255) & ~(size_t)255;
    return r;
  };
  bf16* Wqkv_t = (bf16*)take((size_t)3072 * 1024 * 2);
  bf16* Wo_t = (bf16*)take((size_t)1024 * 1024 * 2);
  bf16* W1_t = (bf16*)take((size_t)4096 * 1024 * 2);
  bf16* W2_t = (bf16*)take((size_t)1024 * 4096 * 2);
  bf16* h1   = (bf16*)take((size_t)4096 * 1024 * 2);
  bf16* qb   = (bf16*)take((size_t)4096 * 1024 * 2);
  bf16* kb   = (bf16*)take((size_t)4096 * 1024 * 2);
  bf16* vtb  = (bf16*)take((size_t)4096 * 1024 * 2);
  bf16* attn = (bf16*)take((size_t)4096 * 1024 * 2);
  float* out1 = (float*)take((size_t)4096 * 1024 * 4);
  bf16* h2   = (bf16*)take((size_t)4096 * 1024 * 2);
  bf16* m1   = (bf16*)take((size_t)4096 * 4096 * 2);

  dim3 blk(256);

  transpose_cast<<<dim3(32, 32), blk, 0, stream>>>(Wq, Wqkv_t, 1024, 1024);
  transpose_cast<<<dim3(32, 32), blk, 0, stream>>>(Wk, Wqkv_t + (size_t)1024 * 1024, 1024, 1024);
  transpose_cast<<<dim3(32, 32), blk, 0, stream>>>(Wv, Wqkv_t + (size_t)2048 * 1024, 1024, 1024);
  transpose_cast<<<dim3(32, 32), blk, 0, stream>>>(Wo, Wo_t, 1024, 1024);
  transpose_cast<<<dim3(128, 32), blk, 0, stream>>>(W1, W1_t, 1024, 4096);
  transpose_cast<<<dim3(32, 128), blk, 0, stream>>>(W2, W2_t, 4096, 1024);

  ln_kernel<<<4096, blk, 0, stream>>>(x, ln1g, ln1b, h1);

  // fused QKV: N = 3072, 1D swizzled grid
  gemm_bf16<0><<<24 * 32, blk, 0, stream>>>(
      h1, Wqkv_t, bq, bk, bv, nullptr, qb, kb, vtb, 4096, 3072, 1024);

  attn_kernel<<<dim3(32, 32), blk, 0, stream>>>(qb, kb, vtb, slim, attn);

  gemm_bf16<3><<<8 * 32, blk, 0, stream>>>(
      attn, Wo_t, bo, nullptr, nullptr, x, out1, nullptr, nullptr, 4096, 1024, 1024);

  ln_kernel<<<4096, blk, 0, stream>>>(out1, ln2g, ln2b, h2);

  gemm_bf16<4><<<32 * 32, blk, 0, stream>>>(
      h2, W1_t, b1, nullptr, nullptr, nullptr, m1, nullptr, nullptr, 4096, 4096, 1024);
  gemm_bf16<5><<<8 * 32, blk, 0, stream>>>(
      m1, W2_t, b2, nullptr, nullptr, out1, (float*)d_out, nullptr, nullptr, 4096, 1024, 4096);
}

// Round 5
// 435.122 us; speedup vs baseline: 1.1733x; 1.1733x over previous
//
#include <hip/hip_runtime.h>
#include <hip/hip_bf16.h>

typedef __hip_bfloat16 bf16;
typedef short bf16x8 __attribute__((ext_vector_type(8)));
typedef float f32x4 __attribute__((ext_vector_type(4)));

__device__ __forceinline__ float gelu_f(float x) {
  return 0.5f * x * (1.f + erff(x * 0.70710678118654752f));
}

__device__ __forceinline__ unsigned short f2bfu(float f) {
  bf16 h = __float2bfloat16(f);
  unsigned short u;
  __builtin_memcpy(&u, &h, 2);
  return u;
}

// async 16B/lane global->LDS; lds dest is wave-uniform base + lane*16
__device__ __forceinline__ void load16_lds(const bf16* g, bf16* l) {
  __builtin_amdgcn_global_load_lds(
      (const __attribute__((address_space(1))) unsigned int*)g,
      (__attribute__((address_space(3))) unsigned int*)l, 16, 0, 0);
}

// ---------------- weight transpose + cast: src fp32 [R][C] -> dst bf16 [C][R]
__global__ __launch_bounds__(256) void transpose_cast(
    const float* __restrict__ src, bf16* __restrict__ dst, int R, int C) {
  __shared__ float tile[32][33];
  int tx = threadIdx.x & 31, ty = threadIdx.x >> 5;  // 32 x 8
  int r0 = blockIdx.y * 32, c0 = blockIdx.x * 32;
  #pragma unroll
  for (int i = ty; i < 32; i += 8)
    tile[i][tx] = src[(size_t)(r0 + i) * C + (c0 + tx)];
  __syncthreads();
  #pragma unroll
  for (int i = ty; i < 32; i += 8)
    dst[(size_t)(c0 + i) * R + (r0 + tx)] = __float2bfloat16(tile[tx][i]);
}

// ---------------- LayerNorm: x fp32 [rows][1024] -> y bf16, one block per row
__global__ __launch_bounds__(256) void ln_kernel(
    const float* __restrict__ x, const float* __restrict__ g,
    const float* __restrict__ b, bf16* __restrict__ y) {
  int row = blockIdx.x;
  int t = threadIdx.x;
  const float4* xr = (const float4*)(x + (size_t)row * 1024);
  float4 v = xr[t];
  float s = v.x + v.y + v.z + v.w;
  float ss = v.x * v.x + v.y * v.y + v.z * v.z + v.w * v.w;
  #pragma unroll
  for (int off = 32; off >= 1; off >>= 1) {
    s += __shfl_xor(s, off);
    ss += __shfl_xor(ss, off);
  }
  __shared__ float red[8];
  int wv = t >> 6;
  if ((t & 63) == 0) { red[wv] = s; red[4 + wv] = ss; }
  __syncthreads();
  float S = red[0] + red[1] + red[2] + red[3];
  float SS = red[4] + red[5] + red[6] + red[7];
  float mu = S * (1.f / 1024.f);
  float var = SS * (1.f / 1024.f) - mu * mu;
  float inv = rsqrtf(var + 1e-5f);
  float4 gv = ((const float4*)g)[t];
  float4 bv = ((const float4*)b)[t];
  ushort4 o;
  o.x = f2bfu((v.x - mu) * inv * gv.x + bv.x);
  o.y = f2bfu((v.y - mu) * inv * gv.y + bv.y);
  o.z = f2bfu((v.z - mu) * inv * gv.z + bv.z);
  o.w = f2bfu((v.w - mu) * inv * gv.w + bv.w);
  ((ushort4*)(y + (size_t)row * 1024))[t] = o;
}

// ---------------- GEMM: C = A[M][K] @ Bt[N][K]^T + bias
// m97 pattern: global_load_lds width-16 staging, non-padded LDS, XOR swizzle,
// double-buffered prefetch. Plain 2D grid (macro-swizzle regressed, R4).
// EPI 0: fused QKV epilogue (block-uniform n0>>10 selects q/k/v layout)
// EPI 3: fp32 out = val + resid
// EPI 4: bf16 out = gelu(val)
// EPI 5: fp32 out = gelu(val) + resid
// EPI 6: split-K partial: bf16 partial[z][m][n] = acc (no bias), K-chunk=1024
template <int EPI>
__global__ __launch_bounds__(256) void gemm_bf16(
    const bf16* __restrict__ A, const bf16* __restrict__ Bt,
    const float* __restrict__ bias0, const float* __restrict__ bias1,
    const float* __restrict__ bias2, const float* __restrict__ resid,
    void* __restrict__ C0, void* __restrict__ C1, void* __restrict__ C2,
    int M, int N, int K) {
  __shared__ __align__(16) bf16 As[2][128 * 32];
  __shared__ __align__(16) bf16 Bs[2][128 * 32];
  const int t = threadIdx.x, lane = t & 63, w = t >> 6;
  const int wm = (w >> 1) * 64, wn = (w & 1) * 64;
  const int m0 = blockIdx.y * 128, n0 = blockIdx.x * 128;

  const int koff = (EPI == 6) ? (int)blockIdx.z * 1024 : 0;
  const int kc_len = (EPI == 6) ? 1024 : K;

  const int srow = lane >> 2;   // row within 16-row staging chunk
  const int sgrp = lane & 3;    // LDS col-group position this lane fills
  f32x4 acc[4][4] = {};

  const bf16* Abase = A + (size_t)m0 * K + koff;
  const bf16* Bbase = Bt + (size_t)n0 * K + koff;

  auto stage = [&](int buf, int kt) {
    #pragma unroll
    for (int c = 0; c < 2; ++c) {
      int row = w * 32 + c * 16 + srow;
      int sw = (row & 3) ^ ((row >> 2) & 3);
      int gg = sgrp ^ sw;  // global col-group this lane fetches (swizzled)
      const bf16* ga = Abase + (size_t)row * K + kt + gg * 8;
      const bf16* gb = Bbase + (size_t)row * K + kt + gg * 8;
      load16_lds(ga, &As[buf][(w * 32 + c * 16) * 32]);
      load16_lds(gb, &Bs[buf][(w * 32 + c * 16) * 32]);
    }
  };

  // fragment read col-group (swizzle inverse), uniform over mc/nc:
  // row = (mult of 16) + (lane&15) -> sw = (lane&3)^((lane>>2)&3)
  const int q8 = (((lane >> 4) ^ (lane & 3) ^ ((lane >> 2) & 3))) * 8;
  const int fr = lane & 15;

  const int nk = kc_len >> 5;
  stage(0, 0);
  for (int i = 0; i < nk; ++i) {
    const int cur = i & 1;
    __syncthreads();  // drains vmcnt (staged loads for cur) + barrier
    if (i + 1 < nk) stage(cur ^ 1, (i + 1) << 5);
    bf16x8 af[4], bfr[4];
    #pragma unroll
    for (int mc = 0; mc < 4; ++mc)
      af[mc] = *(const bf16x8*)&As[cur][(wm + mc * 16 + fr) * 32 + q8];
    #pragma unroll
    for (int nc = 0; nc < 4; ++nc)
      bfr[nc] = *(const bf16x8*)&Bs[cur][(wn + nc * 16 + fr) * 32 + q8];
    #pragma unroll
    for (int mc = 0; mc < 4; ++mc)
      #pragma unroll
      for (int nc = 0; nc < 4; ++nc)
        acc[mc][nc] = __builtin_amdgcn_mfma_f32_16x16x32_bf16(
            af[mc], bfr[nc], acc[mc][nc], 0, 0, 0);
  }

  if constexpr (EPI == 0) {
    const int which = n0 >> 10;  // block-uniform: 0=q, 1=k, 2=v
    const float* bp = which == 0 ? bias0 : which == 1 ? bias1 : bias2;
    bf16* qk = (bf16*)(which == 0 ? C0 : C1);
    #pragma unroll
    for (int mc = 0; mc < 4; ++mc) {
      #pragma unroll
      for (int reg = 0; reg < 4; ++reg) {
        int m = m0 + wm + mc * 16 + ((lane >> 4) << 2) + reg;
        int b = m >> 11, tok = m & 2047;
        #pragma unroll
        for (int nc = 0; nc < 4; ++nc) {
          int n = n0 + wn + nc * 16 + (lane & 15);
          int nn = n & 1023, hh = nn >> 6, d = n & 63;
          float val = acc[mc][nc][reg] + bp[nn];
          if (which == 2)
            ((bf16*)C2)[(size_t)((b * 16 + hh) * 64 + d) * 2048 + tok] =
                __float2bfloat16(val);
          else
            qk[(size_t)((b * 16 + hh) * 2048 + tok) * 64 + d] =
                __float2bfloat16(val);
        }
      }
    }
  } else if constexpr (EPI == 6) {
    bf16* pout = (bf16*)C0 + (size_t)blockIdx.z * M * N;
    #pragma unroll
    for (int mc = 0; mc < 4; ++mc) {
      #pragma unroll
      for (int reg = 0; reg < 4; ++reg) {
        int m = m0 + wm + mc * 16 + ((lane >> 4) << 2) + reg;
        #pragma unroll
        for (int nc = 0; nc < 4; ++nc) {
          int n = n0 + wn + nc * 16 + (lane & 15);
          pout[(size_t)m * N + n] = __float2bfloat16(acc[mc][nc][reg]);
        }
      }
    }
  } else {
    #pragma unroll
    for (int mc = 0; mc < 4; ++mc) {
      #pragma unroll
      for (int reg = 0; reg < 4; ++reg) {
        int m = m0 + wm + mc * 16 + ((lane >> 4) << 2) + reg;
        #pragma unroll
        for (int nc = 0; nc < 4; ++nc) {
          int n = n0 + wn + nc * 16 + (lane & 15);
          float val = acc[mc][nc][reg] + bias0[n];
          size_t idx = (size_t)m * N + n;
          if constexpr (EPI == 3) {
            ((float*)C0)[idx] = val + resid[idx];
          } else if constexpr (EPI == 4) {
            ((bf16*)C0)[idx] = __float2bfloat16(gelu_f(val));
          } else {
            ((float*)C0)[idx] = gelu_f(val) + resid[idx];
          }
        }
      }
    }
  }
}

// ---------------- split-K reduce for MLP2: out = gelu(sum partials + b2) + out1
// partials: 4 x [4096][1024] bf16; one block per row, 4 cols/thread
__global__ __launch_bounds__(256) void reduce_mlp2(
    const bf16* __restrict__ part, const float* __restrict__ b2,
    const float* __restrict__ out1, float* __restrict__ out) {
  const int row = blockIdx.x, t = threadIdx.x;
  const size_t base = (size_t)row * 1024 + t * 4;
  float sum[4] = {0.f, 0.f, 0.f, 0.f};
  #pragma unroll
  for (int kc = 0; kc < 4; ++kc) {
    ushort4 u = *(const ushort4*)(part + (size_t)kc * 4096 * 1024 + base);
    unsigned short us[4] = {u.x, u.y, u.z, u.w};
    #pragma unroll
    for (int j = 0; j < 4; ++j) {
      bf16 h;
      __builtin_memcpy(&h, &us[j], 2);
      sum[j] += __bfloat162float(h);
    }
  }
  float4 bv = ((const float4*)b2)[t];
  float4 rv = *(const float4*)(out1 + base);
  float4 o;
  o.x = gelu_f(sum[0] + bv.x) + rv.x;
  o.y = gelu_f(sum[1] + bv.y) + rv.y;
  o.z = gelu_f(sum[2] + bv.z) + rv.z;
  o.w = gelu_f(sum[3] + bv.w) + rv.w;
  *(float4*)(out + base) = o;
}

// ---------------- Flash attention with off-by-one softmax + head slimming
// Deferred-max variant: p = exp2(z*c) accumulated raw (scores are small; no
// overflow possible for |z| < ~5600). Off-by-one identity:
//   exp(a-m)/(1+sum exp(a-m)) == exp(a)/(exp(m)+sum exp(a))
// so denom = exp2(m*c) + l, reduced ONCE at the end.
// q,k: [B*H][2048][64] bf16 ; vt: [B*H][64][2048] bf16
// attn out: [4096][1024] bf16  (token-major, col = h*64+d)
__global__ __launch_bounds__(256) void attn_kernel(
    const bf16* __restrict__ q, const bf16* __restrict__ k,
    const bf16* __restrict__ vt, const float* __restrict__ slim,
    bf16* __restrict__ attn) {
  __shared__ __align__(16) bf16 Ks[64][64];
  __shared__ __align__(16) bf16 Vs[64][64];
  __shared__ __align__(16) bf16 Ps[4][16][72];

  const int t = threadIdx.x, lane = t & 63, w = t >> 6;
  const int fr = lane & 15, qd = lane >> 4;
  const int bh = blockIdx.y;
  const int q0 = blockIdx.x * 64;
  const size_t bhbase = (size_t)bh * 2048 * 64;

  const int qrow = q0 + w * 16 + fr;
  const bf16* qp = q + bhbase + (size_t)qrow * 64 + qd * 8;
  bf16x8 qf0 = *(const bf16x8*)qp;
  bf16x8 qf1 = *(const bf16x8*)(qp + 32);

  const int srow = lane >> 3;   // 0..7 within 8-row chunk
  const int sg = lane & 7;      // LDS 16B-group position this lane fills

  f32x4 o_acc[4] = {};
  float m_lane[4] = {-3.0e38f, -3.0e38f, -3.0e38f, -3.0e38f};
  float l_lane[4] = {0.f, 0.f, 0.f, 0.f};
  const float C = 0.18033688011f;  // 0.125 * log2(e)

  for (int j0 = 0; j0 < 2048; j0 += 64) {
    __syncthreads();
    #pragma unroll
    for (int c = 0; c < 2; ++c) {
      int r = w * 16 + c * 8 + srow;
      int gk = sg ^ (r & 7);  // swizzled global group
      load16_lds(k + bhbase + (size_t)(j0 + r) * 64 + gk * 8, &Ks[w * 16 + c * 8][0]);
      load16_lds(vt + bhbase + (size_t)r * 2048 + j0 + gk * 8, &Vs[w * 16 + c * 8][0]);
    }
    __syncthreads();

    f32x4 z[4];
    #pragma unroll
    for (int nc = 0; nc < 4; ++nc) {
      int kr = nc * 16 + fr;
      bf16x8 kf0 = *(const bf16x8*)&Ks[kr][(qd ^ (kr & 7)) * 8];
      bf16x8 kf1 = *(const bf16x8*)&Ks[kr][((qd + 4) ^ (kr & 7)) * 8];
      f32x4 zz = {};
      zz = __builtin_amdgcn_mfma_f32_16x16x32_bf16(qf0, kf0, zz, 0, 0, 0);
      zz = __builtin_amdgcn_mfma_f32_16x16x32_bf16(qf1, kf1, zz, 0, 0, 0);
      z[nc] = zz;
    }

    #pragma unroll
    for (int nc = 0; nc < 4; ++nc)
      #pragma unroll
      for (int r = 0; r < 4; ++r) {
        float p = exp2f(z[nc][r] * C);
        l_lane[r] += p;
        m_lane[r] = fmaxf(m_lane[r], z[nc][r]);
        Ps[w][qd * 4 + r][nc * 16 + fr] = __float2bfloat16(p);
      }

    bf16x8 pf0 = *(const bf16x8*)&Ps[w][fr][qd * 8];
    bf16x8 pf1 = *(const bf16x8*)&Ps[w][fr][32 + qd * 8];
    #pragma unroll
    for (int dc = 0; dc < 4; ++dc) {
      int vr = dc * 16 + fr;
      bf16x8 vf0 = *(const bf16x8*)&Vs[vr][(qd ^ (vr & 7)) * 8];
      bf16x8 vf1 = *(const bf16x8*)&Vs[vr][((qd + 4) ^ (vr & 7)) * 8];
      o_acc[dc] = __builtin_amdgcn_mfma_f32_16x16x32_bf16(pf0, vf0, o_acc[dc], 0, 0, 0);
      o_acc[dc] = __builtin_amdgcn_mfma_f32_16x16x32_bf16(pf1, vf1, o_acc[dc], 0, 0, 0);
    }
  }

  #pragma unroll
  for (int off = 1; off <= 8; off <<= 1)
    #pragma unroll
    for (int r = 0; r < 4; ++r) {
      l_lane[r] += __shfl_xor(l_lane[r], off);
      m_lane[r] = fmaxf(m_lane[r], __shfl_xor(m_lane[r], off));
    }

  const int b = bh >> 4, hh = bh & 15;
  const float sl = slim[hh];
  #pragma unroll
  for (int r = 0; r < 4; ++r) {
    float inv = sl / (exp2f(m_lane[r] * C) + l_lane[r]);
    int mrow = b * 2048 + q0 + w * 16 + qd * 4 + r;
    #pragma unroll
    for (int dc = 0; dc < 4; ++dc) {
      int col = hh * 64 + dc * 16 + fr;
      attn[(size_t)mrow * 1024 + col] = __float2bfloat16(o_acc[dc][r] * inv);
    }
  }
}

extern "C" void kernel_launch(void* const* d_in, const int* in_sizes, int n_in,
                              void* d_out, int out_size, void* d_ws, size_t ws_size,
                              hipStream_t stream) {
  const float* x    = (const float*)d_in[0];
  const float* ln1g = (const float*)d_in[1];
  const float* ln1b = (const float*)d_in[2];
  const float* Wq   = (const float*)d_in[3];
  const float* bq   = (const float*)d_in[4];
  const float* Wk   = (const float*)d_in[5];
  const float* bk   = (const float*)d_in[6];
  const float* Wv   = (const float*)d_in[7];
  const float* bv   = (const float*)d_in[8];
  const float* Wo   = (const float*)d_in[9];
  const float* bo   = (const float*)d_in[10];
  const float* slim = (const float*)d_in[11];
  const float* ln2g = (const float*)d_in[12];
  const float* ln2b = (const float*)d_in[13];
  const float* W1   = (const float*)d_in[14];
  const float* b1   = (const float*)d_in[15];
  const float* W2   = (const float*)d_in[16];
  const float* b2   = (const float*)d_in[17];

  char* p = (char*)d_ws;
  auto take = [&](size_t nbytes) {
    char* r = p;
    p += (nbytes + 255) & ~(size_t)255;
    return r;
  };
  bf16* Wqkv_t = (bf16*)take((size_t)3072 * 1024 * 2);
  bf16* Wo_t = (bf16*)take((size_t)1024 * 1024 * 2);
  bf16* W1_t = (bf16*)take((size_t)4096 * 1024 * 2);
  bf16* W2_t = (bf16*)take((size_t)1024 * 4096 * 2);
  bf16* h1   = (bf16*)take((size_t)4096 * 1024 * 2);   // also partial[0]
  bf16* qb   = (bf16*)take((size_t)4096 * 1024 * 2);   // also partial[1]
  bf16* kb   = (bf16*)take((size_t)4096 * 1024 * 2);   // also partial[2]
  bf16* vtb  = (bf16*)take((size_t)4096 * 1024 * 2);   // also partial[3]
  bf16* attn = (bf16*)take((size_t)4096 * 1024 * 2);
  float* out1 = (float*)take((size_t)4096 * 1024 * 4);
  bf16* h2   = (bf16*)take((size_t)4096 * 1024 * 2);
  bf16* m1   = (bf16*)take((size_t)4096 * 4096 * 2);

  // h1..vtb are dead after attn_kernel; reuse as 4x bf16 split-K partials.
  bf16* parts = h1;

  dim3 blk(256);

  transpose_cast<<<dim3(32, 32), blk, 0, stream>>>(Wq, Wqkv_t, 1024, 1024);
  transpose_cast<<<dim3(32, 32), blk, 0, stream>>>(Wk, Wqkv_t + (size_t)1024 * 1024, 1024, 1024);
  transpose_cast<<<dim3(32, 32), blk, 0, stream>>>(Wv, Wqkv_t + (size_t)2048 * 1024, 1024, 1024);
  transpose_cast<<<dim3(32, 32), blk, 0, stream>>>(Wo, Wo_t, 1024, 1024);
  transpose_cast<<<dim3(128, 32), blk, 0, stream>>>(W1, W1_t, 1024, 4096);
  transpose_cast<<<dim3(32, 128), blk, 0, stream>>>(W2, W2_t, 4096, 1024);

  ln_kernel<<<4096, blk, 0, stream>>>(x, ln1g, ln1b, h1);

  // fused QKV: N = 3072
  gemm_bf16<0><<<dim3(24, 32), blk, 0, stream>>>(
      h1, Wqkv_t, bq, bk, bv, nullptr, qb, kb, vtb, 4096, 3072, 1024);

  attn_kernel<<<dim3(32, 32), blk, 0, stream>>>(qb, kb, vtb, slim, attn);

  gemm_bf16<3><<<dim3(8, 32), blk, 0, stream>>>(
      attn, Wo_t, bo, nullptr, nullptr, x, out1, nullptr, nullptr, 4096, 1024, 1024);

  ln_kernel<<<4096, blk, 0, stream>>>(out1, ln2g, ln2b, h2);

  gemm_bf16<4><<<dim3(32, 32), blk, 0, stream>>>(
      h2, W1_t, b1, nullptr, nullptr, nullptr, m1, nullptr, nullptr, 4096, 4096, 1024);

  // MLP2 split-K=4: 1024 blocks (4/CU), bf16 partials, then fused reduce
  gemm_bf16<6><<<dim3(8, 32, 4), blk, 0, stream>>>(
      m1, W2_t, nullptr, nullptr, nullptr, nullptr, parts, nullptr, nullptr,
      4096, 1024, 4096);
  reduce_mlp2<<<4096, blk, 0, stream>>>(parts, b2, out1, (float*)d_out);
}